// Round 1
// baseline (467.939 us; speedup 1.0000x reference)
//
#include <hip/hip_runtime.h>

// DiffPooling on MI355X.
// outputs (f32, concatenated): features_pooled (256x512), assignments (8192x256),
// adjacency_pooled (256x256), link_loss, ent_loss.
// link_loss computed WITHOUT the NxN diff:
//   ||A - sp sp^T||_F^2 = sum(A^2) - 2*tr(adjacency_pooled) + ||sp^T sp||_F^2

typedef unsigned short u16;
typedef __bf16 bf16x8 __attribute__((ext_vector_type(8)));
typedef float f32x4 __attribute__((ext_vector_type(4)));

#define Nn 8192
#define Dd 512
#define Kk 256

__device__ __forceinline__ u16 f2bf(float f) {
  unsigned int u = __builtin_bit_cast(unsigned int, f);
  u += 0x7FFFu + ((u >> 16) & 1u);   // RNE
  return (u16)(u >> 16);
}

// ---------------- generic bf16 MFMA GEMM ----------------
// C(BMxBN f32) = Abf(row-major, lda) @ B(row-major, ldb)  [B f32->bf16 on the fly if !BF16B]
// BM=256 (one thread stages one A row slice), BN=32, BK=32, 256 threads / 4 waves.
// grid: (N/32, M/256, KSPLIT); kchunk = Kin/KSPLIT.
// If !ATOMIC, C += blockIdx.z * zstride (partial buffers). If SUMSQ, atomicAdd sum(B^2).
template <bool BF16B, bool SUMSQ, bool ATOMIC>
__launch_bounds__(256, 4)
__global__ void gemm_kernel(const u16* __restrict__ A, int lda,
                            const void* __restrict__ Bv, int ldb,
                            float* __restrict__ C, int ldc,
                            int kchunk, size_t zstride,
                            float* __restrict__ sumsq) {
  constexpr int BK = 32, PAD = 8;                  // LDS row stride 40 u16 = 80B
  __shared__ alignas(16) u16 As[256][BK + PAD];
  __shared__ alignas(16) u16 Bs[32][BK + PAD];
  __shared__ float sred[4];

  const int tid  = threadIdx.x;
  const int w    = tid >> 6;
  const int lane = tid & 63;
  const int l15  = lane & 15;
  const int g    = lane >> 4;                      // k-group; g8 = g*8
  const int row0 = blockIdx.y * 256;
  const int col0 = blockIdx.x * 32;
  const int kbeg = blockIdx.z * kchunk;
  const int steps = kchunk / BK;
  if (!ATOMIC) C += (size_t)blockIdx.z * zstride;

  const u16* Arow = A + (size_t)(row0 + tid) * lda + kbeg;
  const int kr = tid >> 3, c4 = (tid & 7) * 4;     // B staging map (32 k-rows x 32 cols)

  uint4 ra0, ra1, ra2, ra3;
  float4 rbf;
  uint2 rbu;
  float ss = 0.f;

  auto loadA = [&](int s) {
    const uint4* p = reinterpret_cast<const uint4*>(Arow + s * BK);
    ra0 = p[0]; ra1 = p[1]; ra2 = p[2]; ra3 = p[3];
  };
  auto loadB = [&](int s) {
    size_t off = (size_t)(kbeg + s * BK + kr) * ldb + col0 + c4;
    if constexpr (BF16B) rbu = *reinterpret_cast<const uint2*>((const u16*)Bv + off);
    else                 rbf = *reinterpret_cast<const float4*>((const float*)Bv + off);
  };
  auto storeLDS = [&]() {
    uint4* d = reinterpret_cast<uint4*>(&As[tid][0]);
    d[0] = ra0; d[1] = ra1; d[2] = ra2; d[3] = ra3;
    if constexpr (BF16B) {
      Bs[c4 + 0][kr] = (u16)(rbu.x & 0xffff);
      Bs[c4 + 1][kr] = (u16)(rbu.x >> 16);
      Bs[c4 + 2][kr] = (u16)(rbu.y & 0xffff);
      Bs[c4 + 3][kr] = (u16)(rbu.y >> 16);
    } else {
      Bs[c4 + 0][kr] = f2bf(rbf.x);
      Bs[c4 + 1][kr] = f2bf(rbf.y);
      Bs[c4 + 2][kr] = f2bf(rbf.z);
      Bs[c4 + 3][kr] = f2bf(rbf.w);
      if constexpr (SUMSQ)
        ss += rbf.x * rbf.x + rbf.y * rbf.y + rbf.z * rbf.z + rbf.w * rbf.w;
    }
  };

  f32x4 acc[4][2];
#pragma unroll
  for (int i = 0; i < 4; ++i)
#pragma unroll
    for (int j = 0; j < 2; ++j) acc[i][j] = (f32x4){0.f, 0.f, 0.f, 0.f};

  loadA(0); loadB(0);
  for (int s = 0; s < steps; ++s) {
    __syncthreads();
    storeLDS();
    if (s + 1 < steps) { loadA(s + 1); loadB(s + 1); }   // overlap with MFMA below
    __syncthreads();
    bf16x8 bfr[2], afr[4];
#pragma unroll
    for (int j = 0; j < 2; ++j)
      bfr[j] = *reinterpret_cast<const bf16x8*>(&Bs[j * 16 + l15][g * 8]);
#pragma unroll
    for (int i = 0; i < 4; ++i)
      afr[i] = *reinterpret_cast<const bf16x8*>(&As[w * 64 + i * 16 + l15][g * 8]);
#pragma unroll
    for (int i = 0; i < 4; ++i)
#pragma unroll
      for (int j = 0; j < 2; ++j)
        acc[i][j] = __builtin_amdgcn_mfma_f32_16x16x32_bf16(afr[i], bfr[j], acc[i][j], 0, 0, 0);
  }

  // epilogue: C/D layout (m89-verified): col = lane&15, row = (lane>>4)*4 + reg
#pragma unroll
  for (int i = 0; i < 4; ++i)
#pragma unroll
    for (int j = 0; j < 2; ++j) {
      size_t base = (size_t)(row0 + w * 64 + i * 16 + g * 4) * ldc + col0 + j * 16 + l15;
#pragma unroll
      for (int r = 0; r < 4; ++r) {
        float v = acc[i][j][r];
        float* p = C + base + (size_t)r * ldc;
        if constexpr (ATOMIC) atomicAdd(p, v); else *p = v;
      }
    }

  if constexpr (SUMSQ) {
#pragma unroll
    for (int o = 32; o; o >>= 1) ss += __shfl_xor(ss, o);
    if (lane == 0) sred[w] = ss;
    __syncthreads();
    if (tid == 0) atomicAdd(sumsq, sred[0] + sred[1] + sred[2] + sred[3]);
  }
}

// ---------------- small kernels ----------------
__launch_bounds__(256)
__global__ void cvt_to_bf16(const float* __restrict__ x, u16* __restrict__ y, int n4) {
  int i = blockIdx.x * 256 + threadIdx.x;
  if (i < n4) {
    float4 v = reinterpret_cast<const float4*>(x)[i];
    ushort4 o = {f2bf(v.x), f2bf(v.y), f2bf(v.z), f2bf(v.w)};
    reinterpret_cast<ushort4*>(y)[i] = o;
  }
}

__launch_bounds__(256)
__global__ void softmax_rows(float* __restrict__ io, const float* __restrict__ bias) {
  __shared__ float s1[4], s2[4];
  int n = blockIdx.x, k = threadIdx.x, w = k >> 6;
  size_t idx = (size_t)n * Kk + k;
  float x = io[idx] + bias[k];
  float m = x;
#pragma unroll
  for (int o = 32; o; o >>= 1) m = fmaxf(m, __shfl_xor(m, o));
  if ((k & 63) == 0) s1[w] = m;
  __syncthreads();
  m = fmaxf(fmaxf(s1[0], s1[1]), fmaxf(s1[2], s1[3]));
  float e = __expf(x - m);
  float sum = e;
#pragma unroll
  for (int o = 32; o; o >>= 1) sum += __shfl_xor(sum, o);
  if ((k & 63) == 0) s2[w] = sum;
  __syncthreads();
  sum = s2[0] + s2[1] + s2[2] + s2[3];
  io[idx] = e / sum;
}

__launch_bounds__(256)
__global__ void colsum_k(const float* __restrict__ a, float* __restrict__ cs) {
  int k = threadIdx.x;
  size_t n0 = (size_t)blockIdx.x * 256;
  float s = 0.f;
  for (int i = 0; i < 256; ++i) s += a[(n0 + i) * Kk + k];
  atomicAdd(&cs[k], s);
}

__launch_bounds__(256)
__global__ void make_sp(const float* __restrict__ a, const float* __restrict__ cs,
                        u16* __restrict__ sp, float* __restrict__ ent_sum) {
  __shared__ float s[4];
  int idx = blockIdx.x * 256 + threadIdx.x;          // one float4 per thread
  float4 v = reinterpret_cast<const float4*>(a)[idx];
  int k0 = (idx << 2) & (Kk - 1);
  float p0 = v.x / (cs[k0 + 0] + 1e-8f);
  float p1 = v.y / (cs[k0 + 1] + 1e-8f);
  float p2 = v.z / (cs[k0 + 2] + 1e-8f);
  float p3 = v.w / (cs[k0 + 3] + 1e-8f);
  ushort4 o = {f2bf(p0), f2bf(p1), f2bf(p2), f2bf(p3)};
  reinterpret_cast<ushort4*>(sp)[idx] = o;
  float ent = -(p0 * __logf(p0 + 1e-15f) + p1 * __logf(p1 + 1e-15f) +
                p2 * __logf(p2 + 1e-15f) + p3 * __logf(p3 + 1e-15f));
#pragma unroll
  for (int oo = 32; oo; oo >>= 1) ent += __shfl_xor(ent, oo);
  if ((threadIdx.x & 63) == 0) s[threadIdx.x >> 6] = ent;
  __syncthreads();
  if (threadIdx.x == 0) atomicAdd(ent_sum, s[0] + s[1] + s[2] + s[3]);
}

__launch_bounds__(256)
__global__ void make_spT(const float* __restrict__ a, const float* __restrict__ cs,
                         u16* __restrict__ spT) {
  __shared__ float t[64][65];
  int n0 = blockIdx.x * 64, k0 = blockIdx.y * 64;
  int c = threadIdx.x & 63, r = threadIdx.x >> 6;
#pragma unroll
  for (int i = 0; i < 16; ++i) {
    int n = r + i * 4;
    t[c][n] = a[(size_t)(n0 + n) * Kk + k0 + c];
  }
  __syncthreads();
#pragma unroll
  for (int i = 0; i < 16; ++i) {
    int kk = r + i * 4;
    float inv = 1.f / (cs[k0 + kk] + 1e-8f);
    spT[(size_t)(k0 + kk) * Nn + n0 + c] = f2bf(t[kk][c] * inv);
  }
}

__launch_bounds__(256)
__global__ void combine_P(const float* __restrict__ P0, const float* __restrict__ P1,
                          u16* __restrict__ Pbf) {
  int idx = blockIdx.x * 256 + threadIdx.x;
  float4 a = reinterpret_cast<const float4*>(P0)[idx];
  float4 b = reinterpret_cast<const float4*>(P1)[idx];
  ushort4 o = {f2bf(a.x + b.x), f2bf(a.y + b.y), f2bf(a.z + b.z), f2bf(a.w + b.w)};
  reinterpret_cast<ushort4*>(Pbf)[idx] = o;
}

__launch_bounds__(256)
__global__ void finalize_k(const float* __restrict__ ap, const float* __restrict__ spTsp,
                           const float* __restrict__ scal,
                           float* __restrict__ olink, float* __restrict__ oent) {
  __shared__ float s1[4], s2[4];
  int t = threadIdx.x;
  float tr = ap[t * (Kk + 1)];
#pragma unroll
  for (int o = 32; o; o >>= 1) tr += __shfl_xor(tr, o);
  if ((t & 63) == 0) s1[t >> 6] = tr;
  __syncthreads();
  float trace = s1[0] + s1[1] + s1[2] + s1[3];
  float fr = 0.f;
  for (int i = t; i < Kk * Kk; i += 256) { float v = spTsp[i]; fr += v * v; }
#pragma unroll
  for (int o = 32; o; o >>= 1) fr += __shfl_xor(fr, o);
  if ((t & 63) == 0) s2[t >> 6] = fr;
  __syncthreads();
  float fro = s2[0] + s2[1] + s2[2] + s2[3];
  if (t == 0) {
    float val = scal[0] - 2.f * trace + fro;
    *olink = sqrtf(fmaxf(val, 0.f)) / ((float)Nn * (float)Nn);
    *oent  = scal[1] / (float)Nn;
  }
}

// ---------------- launch ----------------
extern "C" void kernel_launch(void* const* d_in, const int* in_sizes, int n_in,
                              void* d_out, int out_size, void* d_ws, size_t ws_size,
                              hipStream_t stream) {
  const float* F    = (const float*)d_in[0];   // 8192x512
  const float* Adj  = (const float*)d_in[1];   // 8192x8192
  const float* W    = (const float*)d_in[2];   // 512x256
  const float* bias = (const float*)d_in[3];   // 256
  float* out = (float*)d_out;

  char* ws = (char*)d_ws;
  u16*  Fbf   = (u16*)(ws + 0);            // 8 MB (later reused as P0)
  u16*  Wbf   = (u16*)(ws + 8388608);      // 256 KB
  u16*  spb   = (u16*)(ws + 8650752);      // 4 MB  sp bf16 (N x K)
  u16*  spT   = (u16*)(ws + 12845056);     // 4 MB  sp^T bf16 (K x N)
  u16*  Pbf   = (u16*)(ws + 17039360);     // 4 MB  P bf16 (K x N)
  float* P1   = (float*)(ws + 21233664);   // 8 MB
  float* P0   = (float*)(ws + 0);          // overlays Fbf (after last Fbf use)
  float* spTsp= (float*)(ws + 29622272);   // 256 KB
  float* cs   = (float*)(ws + 29884416);   // 1 KB
  float* scal = (float*)(ws + 29885440);   // [0]=sumA2 [1]=ent_sum

  float* fpool  = out;                 // 131072
  float* assign = out + 131072;        // 2097152
  float* apool  = out + 2228224;       // 65536
  float* olink  = out + 2293760;
  float* oent   = out + 2293761;

  const size_t ZSTRIDE = 21233664 / 4; // P1 - P0 in floats

  hipMemsetAsync(fpool, 0, 131072 * 4, stream);
  hipMemsetAsync(apool, 0, 65536 * 4, stream);
  hipMemsetAsync(spTsp, 0, 65536 * 4, stream);
  hipMemsetAsync(cs,    0, 256 * 4,   stream);
  hipMemsetAsync(scal,  0, 2 * 4,     stream);

  cvt_to_bf16<<<4096, 256, 0, stream>>>(F, Fbf, 1048576);
  cvt_to_bf16<<<128, 256, 0, stream>>>(W, Wbf, 32768);

  // G1: logits = F @ W   (into assignments slot, then softmax in place)
  gemm_kernel<true, false, false><<<dim3(8, 32, 1), 256, 0, stream>>>(
      Fbf, Dd, Wbf, Kk, assign, Kk, Dd, 0, nullptr);
  softmax_rows<<<Nn, 256, 0, stream>>>(assign, bias);
  colsum_k<<<32, 256, 0, stream>>>(assign, cs);
  make_sp<<<2048, 256, 0, stream>>>(assign, cs, spb, &scal[1]);
  make_spT<<<dim3(128, 4), 256, 0, stream>>>(assign, cs, spT);

  // G4: features_pooled = sp^T @ F   (atomic over 8 k-chunks; uses Fbf LAST)
  gemm_kernel<true, false, true><<<dim3(16, 1, 8), 256, 0, stream>>>(
      spT, Nn, Fbf, Dd, fpool, Dd, 1024, 0, nullptr);
  // G5: spTsp = sp^T @ sp
  gemm_kernel<true, false, true><<<dim3(8, 1, 8), 256, 0, stream>>>(
      spT, Nn, spb, Kk, spTsp, Kk, 1024, 0, nullptr);
  // G2: P = sp^T @ A  (big one; 2 partial buffers, fused sum(A^2))
  gemm_kernel<false, true, false><<<dim3(256, 1, 2), 256, 0, stream>>>(
      spT, Nn, Adj, Nn, P0, Nn, 4096, ZSTRIDE, &scal[0]);
  combine_P<<<2048, 256, 0, stream>>>(P0, P1, Pbf);
  // G3: adjacency_pooled = P @ sp
  gemm_kernel<true, false, true><<<dim3(8, 1, 8), 256, 0, stream>>>(
      Pbf, Nn, spb, Kk, apool, Kk, 1024, 0, nullptr);

  finalize_k<<<1, 256, 0, stream>>>(apool, spTsp, scal, olink, oent);
}

// Round 4
// 334.101 us; speedup vs baseline: 1.4006x; 1.4006x over previous
//
#include <hip/hip_runtime.h>

// DiffPooling on MI355X (gfx950).
// outputs f32 concat: features_pooled (256x512), assignments (8192x256),
// adjacency_pooled (256x256), link_loss, ent_loss.
// link_loss: ||A - sp sp^T||_F^2 = sum(A^2) - 2*tr(adj_pooled) + ||sp^T sp||_F^2
//
// All MFMA A-operands live in "panel" format: for logical [M][Kin] bf16,
// panel p = k/32, m-block b = m/256:
//   offset_u16((b,p), m, k) = ((b*(Kin/32)+p)*256 + m%256)*40 + (k%32)
// 40-u16 (80 B) row stride -> global_load_lds-linear AND 2-way-max LDS banks.

typedef unsigned short u16;
typedef __bf16 bf16x8 __attribute__((ext_vector_type(8)));
typedef float f32x4 __attribute__((ext_vector_type(4)));
typedef float float8_t __attribute__((ext_vector_type(8)));
typedef unsigned short ushort8_t __attribute__((ext_vector_type(8)));

#define Nn 8192
#define Dd 512
#define Kk 256

__device__ __forceinline__ u16 f2bf(float f) {
  unsigned int u = __builtin_bit_cast(unsigned int, f);
  u += 0x7FFFu + ((u >> 16) & 1u);   // RNE
  return (u16)(u >> 16);
}
__device__ __forceinline__ float bf2f(u16 h) {
  return __builtin_bit_cast(float, (unsigned int)h << 16);
}
__device__ __forceinline__ void gll16(const void* g, void* l) {
  __builtin_amdgcn_global_load_lds(
      (const __attribute__((address_space(1))) unsigned int*)g,
      (__attribute__((address_space(3))) unsigned int*)l, 16, 0, 0);
}

template <bool B> struct BRegSel { typedef float8_t T; };
template <> struct BRegSel<true> { typedef ushort8_t T; };

// ---------------- panel-A bf16 MFMA GEMM ----------------
// C(256 x 64 per block) = Apanel @ B(row-major, ldb; f32->bf16 on the fly if !BF16B)
// 256 threads / 4 waves, wave tile 64x64, BK=32, double-buffered LDS, 1 barrier/step.
// OUTKIND: 0 = f32 store via LDS (G1), 1 = bf16 store via LDS + z-partials (G2),
//          2 = atomic f32 (G4/G5/G3).
template <bool BF16B, bool SUMSQ, int OUTKIND>
__launch_bounds__(256, 2)
__global__ void gemm2(const u16* __restrict__ Apan, int ppmb,
                      const void* __restrict__ Bv, int ldb,
                      void* __restrict__ Cv, int ldc,
                      int kchunk, size_t zstride,
                      float* __restrict__ sumsq, int swz) {
  __shared__ alignas(16) u16 SH[2 * 10240 + 2 * 2560];  // As0 As1 Bs0 Bs1
  __shared__ float sred[4];

  int bx = blockIdx.x, bz = blockIdx.z;
  if (swz) {  // XCD-chunked bijective remap (total % 8 == 0)
    int gx = gridDim.x, tot = gx * gridDim.z;
    int f = bx + gx * bz;
    int l = (f & 7) * (tot >> 3) + (f >> 3);
    bx = l % gx; bz = l / gx;
  }
  const int tid = threadIdx.x, wv = tid >> 6, lane = tid & 63;
  const int l15 = lane & 15, g = lane >> 4;
  const int col0 = bx * 64;
  const int row0 = blockIdx.y * 256;
  const int kbeg = bz * kchunk;
  const int steps = kchunk >> 5;
  const u16* pbase = Apan + (size_t)(blockIdx.y * ppmb + (kbeg >> 5)) * 10240;

  float ss = 0.f;
  typename BRegSel<BF16B>::T rbA, rbB;

  auto loadB = [&](auto& rb, int t) {   // thread owns column (col0+lane), rows wv*8..+7
    const int kq = kbeg + t * 32 + wv * 8;
    if constexpr (BF16B) {
      const u16* p = (const u16*)Bv + (size_t)kq * ldb + col0 + lane;
#pragma unroll
      for (int i = 0; i < 8; ++i) rb[i] = p[(size_t)i * ldb];
    } else {
      const float* p = (const float*)Bv + (size_t)kq * ldb + col0 + lane;
#pragma unroll
      for (int i = 0; i < 8; ++i) rb[i] = p[(size_t)i * ldb];
    }
  };
  auto storeB = [&](int buf, auto& rb) {  // pack 8 k-elems of one col -> one b128
    ushort8_t h;
    if constexpr (BF16B) {
      h = rb;
    } else {
#pragma unroll
      for (int i = 0; i < 8; ++i) {
        h[i] = f2bf(rb[i]);
        if constexpr (SUMSQ) ss += rb[i] * rb[i];
      }
    }
    *(uint4*)&SH[20480 + buf * 2560 + lane * 40 + wv * 8] = __builtin_bit_cast(uint4, h);
  };
  auto gllA = [&](int buf, int t) {      // 20 KB panel -> LDS, linear, coalesced
    const char* gp = (const char*)(pbase + (size_t)t * 10240) + wv * 1024 + lane * 16;
    char* lp = (char*)&SH[buf * 10240] + wv * 1024;
#pragma unroll
    for (int r = 0; r < 5; ++r) gll16(gp + r * 4096, lp + r * 4096);
  };

  f32x4 acc[4][4];
#pragma unroll
  for (int i = 0; i < 4; ++i)
#pragma unroll
    for (int j = 0; j < 4; ++j) acc[i][j] = (f32x4){0.f, 0.f, 0.f, 0.f};

  auto comp = [&](int buf) {
    const u16* as = &SH[buf * 10240];
    const u16* bs = &SH[20480 + buf * 2560];
    bf16x8 afr[4], bfr[4];
#pragma unroll
    for (int j = 0; j < 4; ++j)
      bfr[j] = *(const bf16x8*)(bs + (j * 16 + l15) * 40 + g * 8);
#pragma unroll
    for (int i = 0; i < 4; ++i)
      afr[i] = *(const bf16x8*)(as + (wv * 64 + i * 16 + l15) * 40 + g * 8);
#pragma unroll
    for (int i = 0; i < 4; ++i)
#pragma unroll
      for (int j = 0; j < 4; ++j)
        acc[i][j] = __builtin_amdgcn_mfma_f32_16x16x32_bf16(afr[i], bfr[j], acc[i][j], 0, 0, 0);
  };

  // prologue: stage tile0 fully, prefetch tile1 B-regs
  loadB(rbA, 0);
  gllA(0, 0);
  storeB(0, rbA);
  loadB(rbA, 1);
  __syncthreads();

  for (int t = 0; t < steps; t += 2) {
    if (t + 2 < steps) loadB(rbB, t + 2);
    if (t + 1 < steps) { gllA(1, t + 1); storeB(1, rbA); }
    comp(0);
    __syncthreads();
    if (t + 3 < steps) loadB(rbA, t + 3);
    if (t + 2 < steps) { gllA(0, t + 2); storeB(0, rbB); }
    if (t + 1 < steps) comp(1);
    __syncthreads();
  }

  // epilogues (C/D layout m89-verified: col = j*16+l15, row = wv*64+i*16+g*4+r)
  if constexpr (OUTKIND == 0) {          // f32 via LDS, two 128-row halves
    float* sf = (float*)SH;              // [128][68] f32
#pragma unroll
    for (int h = 0; h < 2; ++h) {
      __syncthreads();
      if ((wv >> 1) == h) {
#pragma unroll
        for (int i = 0; i < 4; ++i)
#pragma unroll
          for (int j = 0; j < 4; ++j)
#pragma unroll
            for (int r = 0; r < 4; ++r)
              sf[((wv & 1) * 64 + i * 16 + g * 4 + r) * 68 + j * 16 + l15] = acc[i][j][r];
      }
      __syncthreads();
#pragma unroll
      for (int e = 0; e < 8; ++e) {     // 2048 float4s = full 128x64 tile
        int idx2 = tid + e * 256;
        int m = idx2 >> 4, c4 = (idx2 & 15) * 4;
        float4 v = *(const float4*)(sf + m * 68 + c4);
        *(float4*)((float*)Cv + (size_t)(row0 + h * 128 + m) * ldc + col0 + c4) = v;
      }
    }
  } else if constexpr (OUTKIND == 1) {   // bf16 z-partial via LDS
    u16* C = (u16*)Cv + (size_t)bz * zstride;
    u16* sb = SH;                        // [256][72] u16 (stride 72: 64 cols + pad)
#pragma unroll
    for (int i = 0; i < 4; ++i)
#pragma unroll
      for (int j = 0; j < 4; ++j)
#pragma unroll
        for (int r = 0; r < 4; ++r)
          sb[(wv * 64 + i * 16 + g * 4 + r) * 72 + j * 16 + l15] = f2bf(acc[i][j][r]);
    __syncthreads();
#pragma unroll
    for (int e = 0; e < 8; ++e) {
      int m = (tid >> 3) + e * 32;
      uint4 v = *(const uint4*)(sb + m * 72 + (tid & 7) * 8);
      *(uint4*)(C + (size_t)m * ldc + col0 + (tid & 7) * 8) = v;
    }
  } else {                               // atomic f32
    float* C = (float*)Cv;
#pragma unroll
    for (int i = 0; i < 4; ++i)
#pragma unroll
      for (int j = 0; j < 4; ++j) {
        size_t base = (size_t)(row0 + wv * 64 + i * 16 + g * 4) * ldc + col0 + j * 16 + l15;
#pragma unroll
        for (int r = 0; r < 4; ++r) atomicAdd(C + base + (size_t)r * ldc, acc[i][j][r]);
      }
  }

  if constexpr (SUMSQ) {
#pragma unroll
    for (int o = 32; o; o >>= 1) ss += __shfl_xor(ss, o);
    if (lane == 0) sred[wv] = ss;
    __syncthreads();
    if (tid == 0) atomicAdd(sumsq, sred[0] + sred[1] + sred[2] + sred[3]);
  }
}

// ---------------- producers / small kernels ----------------
__launch_bounds__(256)
__global__ void cvtF_panel(const float* __restrict__ F, u16* __restrict__ pan) {
  int idx = blockIdx.x * 256 + threadIdx.x;      // 524288 groups of 8
  int m = idx >> 6, k0 = (idx & 63) * 8;
  float4 a = *(const float4*)(F + (size_t)m * Dd + k0);
  float4 b = *(const float4*)(F + (size_t)m * Dd + k0 + 4);
  ushort8_t h;
  h[0] = f2bf(a.x); h[1] = f2bf(a.y); h[2] = f2bf(a.z); h[3] = f2bf(a.w);
  h[4] = f2bf(b.x); h[5] = f2bf(b.y); h[6] = f2bf(b.z); h[7] = f2bf(b.w);
  int mb = m >> 8, mr = m & 255, p = k0 >> 5, c = k0 & 31;
  *(uint4*)(pan + ((size_t)(mb * 16 + p) * 256 + mr) * 40 + c) = __builtin_bit_cast(uint4, h);
}

__launch_bounds__(256)
__global__ void cvt_to_bf16(const float* __restrict__ x, u16* __restrict__ y, int n4) {
  int i = blockIdx.x * 256 + threadIdx.x;
  if (i < n4) {
    float4 v = reinterpret_cast<const float4*>(x)[i];
    ushort4 o = {f2bf(v.x), f2bf(v.y), f2bf(v.z), f2bf(v.w)};
    reinterpret_cast<ushort4*>(y)[i] = o;
  }
}

__launch_bounds__(256)
__global__ void softmax_rows(float* __restrict__ io, const float* __restrict__ bias) {
  __shared__ float s1[4], s2[4];
  int n = blockIdx.x, k = threadIdx.x, w = k >> 6;
  size_t idx = (size_t)n * Kk + k;
  float x = io[idx] + bias[k];
  float m = x;
#pragma unroll
  for (int o = 32; o; o >>= 1) m = fmaxf(m, __shfl_xor(m, o));
  if ((k & 63) == 0) s1[w] = m;
  __syncthreads();
  m = fmaxf(fmaxf(s1[0], s1[1]), fmaxf(s1[2], s1[3]));
  float e = __expf(x - m);
  float sum = e;
#pragma unroll
  for (int o = 32; o; o >>= 1) sum += __shfl_xor(sum, o);
  if ((k & 63) == 0) s2[w] = sum;
  __syncthreads();
  sum = s2[0] + s2[1] + s2[2] + s2[3];
  io[idx] = e / sum;
}

__launch_bounds__(256)
__global__ void colsum_k(const float* __restrict__ a, float* __restrict__ cs) {
  int k = threadIdx.x;
  size_t n0 = (size_t)blockIdx.x * 32;
  float s = 0.f;
  for (int i = 0; i < 32; ++i) s += a[(n0 + i) * Kk + k];
  atomicAdd(&cs[k], s);
}

__launch_bounds__(256)
__global__ void make_sp(const float* __restrict__ a, const float* __restrict__ cs,
                        u16* __restrict__ sp, float* __restrict__ ent_sum) {
  __shared__ float s[4];
  int idx = blockIdx.x * 256 + threadIdx.x;
  float4 v = reinterpret_cast<const float4*>(a)[idx];
  int k0 = (idx << 2) & (Kk - 1);
  float p0 = v.x / (cs[k0 + 0] + 1e-8f);
  float p1 = v.y / (cs[k0 + 1] + 1e-8f);
  float p2 = v.z / (cs[k0 + 2] + 1e-8f);
  float p3 = v.w / (cs[k0 + 3] + 1e-8f);
  ushort4 o = {f2bf(p0), f2bf(p1), f2bf(p2), f2bf(p3)};
  reinterpret_cast<ushort4*>(sp)[idx] = o;
  float ent = -(p0 * __logf(p0 + 1e-15f) + p1 * __logf(p1 + 1e-15f) +
                p2 * __logf(p2 + 1e-15f) + p3 * __logf(p3 + 1e-15f));
#pragma unroll
  for (int oo = 32; oo; oo >>= 1) ent += __shfl_xor(ent, oo);
  if ((threadIdx.x & 63) == 0) s[threadIdx.x >> 6] = ent;
  __syncthreads();
  if (threadIdx.x == 0) atomicAdd(ent_sum, s[0] + s[1] + s[2] + s[3]);
}

// spT panel: block p handles n in [32p,32p+32), thread = k. Coalesced reads.
__launch_bounds__(256)
__global__ void make_spT_panel(const float* __restrict__ a, const float* __restrict__ cs,
                               u16* __restrict__ pan) {
  int p = blockIdx.x, k = threadIdx.x;
  float inv = 1.f / (cs[k] + 1e-8f);
  int n0 = p * 32;
  ushort8_t h0, h1, h2, h3;
#pragma unroll
  for (int j = 0; j < 8; ++j) h0[j] = f2bf(a[(size_t)(n0 + j) * Kk + k] * inv);
#pragma unroll
  for (int j = 0; j < 8; ++j) h1[j] = f2bf(a[(size_t)(n0 + 8 + j) * Kk + k] * inv);
#pragma unroll
  for (int j = 0; j < 8; ++j) h2[j] = f2bf(a[(size_t)(n0 + 16 + j) * Kk + k] * inv);
#pragma unroll
  for (int j = 0; j < 8; ++j) h3[j] = f2bf(a[(size_t)(n0 + 24 + j) * Kk + k] * inv);
  u16* dst = pan + ((size_t)p * 256 + k) * 40;
  *(uint4*)(dst + 0)  = __builtin_bit_cast(uint4, h0);
  *(uint4*)(dst + 8)  = __builtin_bit_cast(uint4, h1);
  *(uint4*)(dst + 16) = __builtin_bit_cast(uint4, h2);
  *(uint4*)(dst + 24) = __builtin_bit_cast(uint4, h3);
}

// sum 4 bf16 partials -> Pbf panel
__launch_bounds__(256)
__global__ void combine_P(const u16* __restrict__ part, u16* __restrict__ pan) {
  int idx = blockIdx.x * 256 + threadIdx.x;      // 262144
  int m = idx >> 10, kk8 = idx & 1023;
  size_t off = (size_t)m * Nn + kk8 * 8;
  float8_t s = {0.f, 0.f, 0.f, 0.f, 0.f, 0.f, 0.f, 0.f};
#pragma unroll
  for (int z = 0; z < 4; ++z) {
    ushort8_t v = __builtin_bit_cast(ushort8_t,
        *(const uint4*)(part + (size_t)z * Kk * Nn + off));
#pragma unroll
    for (int j = 0; j < 8; ++j) s[j] += bf2f(v[j]);
  }
  ushort8_t h;
#pragma unroll
  for (int j = 0; j < 8; ++j) h[j] = f2bf(s[j]);
  int p = kk8 >> 2, c = (kk8 & 3) * 8;
  *(uint4*)(pan + ((size_t)p * 256 + m) * 40 + c) = __builtin_bit_cast(uint4, h);
}

__launch_bounds__(256)
__global__ void finalize_k(const float* __restrict__ ap, const float* __restrict__ spTsp,
                           const float* __restrict__ scal,
                           float* __restrict__ olink, float* __restrict__ oent) {
  __shared__ float s1[4], s2[4];
  int t = threadIdx.x;
  float tr = ap[t * (Kk + 1)];
#pragma unroll
  for (int o = 32; o; o >>= 1) tr += __shfl_xor(tr, o);
  if ((t & 63) == 0) s1[t >> 6] = tr;
  __syncthreads();
  float trace = s1[0] + s1[1] + s1[2] + s1[3];
  float fr = 0.f;
  for (int i = t; i < Kk * Kk; i += 256) { float v = spTsp[i]; fr += v * v; }
#pragma unroll
  for (int o = 32; o; o >>= 1) fr += __shfl_xor(fr, o);
  if ((t & 63) == 0) s2[t >> 6] = fr;
  __syncthreads();
  float fro = s2[0] + s2[1] + s2[2] + s2[3];
  if (t == 0) {
    float val = scal[0] - 2.f * trace + fro;
    *olink = sqrtf(fmaxf(val, 0.f)) / ((float)Nn * (float)Nn);
    *oent  = scal[1] / (float)Nn;
  }
}

// ---------------- launch ----------------
extern "C" void kernel_launch(void* const* d_in, const int* in_sizes, int n_in,
                              void* d_out, int out_size, void* d_ws, size_t ws_size,
                              hipStream_t stream) {
  const float* F    = (const float*)d_in[0];
  const float* Adj  = (const float*)d_in[1];
  const float* W    = (const float*)d_in[2];
  const float* bias = (const float*)d_in[3];
  float* out = (float*)d_out;
  char* ws = (char*)d_ws;

  u16*  FbfPan = (u16*)(ws + 0);           // 10.5 MB (overlaid by partials after G1)
  u16*  parts  = (u16*)(ws + 0);           // 4 x 4 MB bf16 partials
  u16*  Wbf    = (u16*)(ws + 16777216);    // 256 KB
  u16*  spb    = (u16*)(ws + 17039360);    // 4 MB
  u16*  spTpan = (u16*)(ws + 21233664);    // 5.25 MB
  u16*  Ppan   = (u16*)(ws + 26476544);    // 5.25 MB
  float* cs    = (float*)(ws + 31719424);  // 1 KB
  float* spTsp = (float*)(ws + 31720448);  // 256 KB
  float* scal  = (float*)(ws + 31982592);  // [0]=sumA2 [1]=ent

  float* fpool  = out;
  float* assign = out + 131072;
  float* apool  = out + 2228224;
  float* olink  = out + 2293760;
  float* oent   = out + 2293761;

  (void)hipMemsetAsync(fpool, 0, 131072 * 4, stream);
  (void)hipMemsetAsync(apool, 0, 65536 * 4, stream);
  (void)hipMemsetAsync(spTsp, 0, 65536 * 4, stream);
  (void)hipMemsetAsync(cs,    0, 256 * 4,   stream);
  (void)hipMemsetAsync(scal,  0, 8,         stream);

  cvtF_panel<<<2048, 256, 0, stream>>>(F, FbfPan);
  cvt_to_bf16<<<128, 256, 0, stream>>>(W, Wbf, 32768);

  // G1: logits = F @ W  -> assign (f32), then softmax in place
  gemm2<true, false, 0><<<dim3(4, 32, 1), 256, 0, stream>>>(
      FbfPan, 16, Wbf, Kk, assign, Kk, Dd, 0, nullptr, 0);
  softmax_rows<<<Nn, 256, 0, stream>>>(assign, bias);
  colsum_k<<<256, 256, 0, stream>>>(assign, cs);
  make_sp<<<2048, 256, 0, stream>>>(assign, cs, spb, &scal[1]);
  make_spT_panel<<<256, 256, 0, stream>>>(assign, cs, spTpan);

  // G4: features_pooled = spT @ F (atomic over 16 k-chunks; B = F f32 directly)
  gemm2<false, false, 2><<<dim3(8, 1, 16), 256, 0, stream>>>(
      spTpan, 256, F, Dd, fpool, Dd, Nn / 16, 0, nullptr, 0);
  // G5: spTsp = spT @ sp
  gemm2<true, false, 2><<<dim3(4, 1, 16), 256, 0, stream>>>(
      spTpan, 256, spb, Kk, spTsp, Kk, Nn / 16, 0, nullptr, 0);
  // G2: P = spT @ A (the big one): 4 bf16 partials + fused sum(A^2), XCD swizzle
  gemm2<false, true, 1><<<dim3(128, 1, 4), 256, 0, stream>>>(
      spTpan, 256, Adj, Nn, parts, Nn, Nn / 4, (size_t)Kk * Nn, &scal[0], 1);
  combine_P<<<1024, 256, 0, stream>>>(parts, Ppan);
  // G3: adjacency_pooled = P @ sp
  gemm2<true, false, 2><<<dim3(4, 1, 16), 256, 0, stream>>>(
      Ppan, 256, spb, Kk, apool, Kk, Nn / 16, 0, nullptr, 0);

  finalize_k<<<1, 256, 0, stream>>>(apool, spTsp, scal, olink, oent);
}

// Round 5
// 313.153 us; speedup vs baseline: 1.4943x; 1.0669x over previous
//
#include <hip/hip_runtime.h>

// DiffPooling on MI355X (gfx950).
// outputs f32 concat: features_pooled (256x512), assignments (8192x256),
// adjacency_pooled (256x256), link_loss, ent_loss.
// link_loss: ||A - sp sp^T||_F^2 = sum(A^2) - 2*tr(adj_pooled) + ||sp^T sp||_F^2
//
// MFMA A-operands in "panel" format: for logical [M][Kin] bf16,
// panel p = k/32, m-block b = m/256:
//   offset_u16((b,p), m, k) = ((b*(Kin/32)+p)*256 + m%256)*32 + (k%32)
// (32-u16 rows, no pad: global_load_lds-linear; b128 reads at the 8-cy floor)

typedef unsigned short u16;
typedef __bf16 bf16x8 __attribute__((ext_vector_type(8)));
typedef float f32x4 __attribute__((ext_vector_type(4)));
typedef float float8_t __attribute__((ext_vector_type(8)));
typedef unsigned short ushort8_t __attribute__((ext_vector_type(8)));

#define Nn 8192
#define Dd 512
#define Kk 256

__device__ __forceinline__ u16 f2bf(float f) {
  unsigned int u = __builtin_bit_cast(unsigned int, f);
  u += 0x7FFFu + ((u >> 16) & 1u);   // RNE
  return (u16)(u >> 16);
}
__device__ __forceinline__ float bf2f(u16 h) {
  return __builtin_bit_cast(float, (unsigned int)h << 16);
}
__device__ __forceinline__ void gll16(const void* g, void* l) {
  __builtin_amdgcn_global_load_lds(
      (const __attribute__((address_space(1))) unsigned int*)g,
      (__attribute__((address_space(3))) unsigned int*)l, 16, 0, 0);
}

template <bool B> struct BRegSel { typedef float8_t T; };
template <> struct BRegSel<true> { typedef ushort8_t T; };

// ---------------- panel-A bf16 MFMA GEMM, counted-vmcnt pipeline ----------------
// C(256 x 64 per block) = Apanel @ B(row-major, ldb; f32->bf16 on the fly if !BF16B)
// 256 threads / 4 waves, wave tile 64x64, BK=32, double-buffered LDS.
// Per step: gllA(next)[4 vmem] ; storeB(cur) ; loadB(t+2)[8 vmem] ;
//           s_waitcnt vmcnt(20) ; s_barrier ; MFMA ; s_barrier.
// vmcnt(20) = keep {A(t+1):4 + B(t+2):8 + B(t+1)... exactly the newest 20} in
// flight, drain only the current A-tile. Tails clamp tile index (uniform CF).
// OUTKIND: 0 = f32 store via LDS (G1), 1 = bf16 z-partial via LDS (G2),
//          2 = atomic f32 (G4/G5/G3).
template <bool BF16B, bool SUMSQ, int OUTKIND>
__launch_bounds__(256, 3)
__global__ void gemm2(const u16* __restrict__ Apan, int ppmb,
                      const void* __restrict__ Bv, int ldb,
                      void* __restrict__ Cv, int ldc,
                      int kchunk, size_t zstride,
                      float* __restrict__ sumsq, int swz) {
  __shared__ alignas(16) u16 SH[2 * 8192 + 2 * 2048];  // As0 As1 Bs0 Bs1
  __shared__ float sred[4];

  int bx = blockIdx.x, bz = blockIdx.z;
  if (swz) {  // XCD-chunked bijective remap (total % 8 == 0)
    int gx = gridDim.x, tot = gx * gridDim.z;
    int f = bx + gx * bz;
    int l = (f & 7) * (tot >> 3) + (f >> 3);
    bx = l % gx; bz = l / gx;
  }
  const int tid = threadIdx.x, wv = tid >> 6, lane = tid & 63;
  const int l15 = lane & 15, g = lane >> 4;
  const int col0 = bx * 64;
  const int row0 = blockIdx.y * 256;
  const int kbeg = bz * kchunk;
  const int steps = kchunk >> 5;
  const u16* pbase = Apan + (size_t)(blockIdx.y * ppmb + (kbeg >> 5)) * 8192;

  float ss = 0.f;
  typename BRegSel<BF16B>::T rbE, rbO;

  auto loadB = [&](auto& rb, int t) {   // thread owns column (col0+lane), rows wv*8..+7
    const int kq = kbeg + t * 32 + wv * 8;
    if constexpr (BF16B) {
      const u16* p = (const u16*)Bv + (size_t)kq * ldb + col0 + lane;
#pragma unroll
      for (int i = 0; i < 8; ++i) rb[i] = p[(size_t)i * ldb];
    } else {
      const float* p = (const float*)Bv + (size_t)kq * ldb + col0 + lane;
#pragma unroll
      for (int i = 0; i < 8; ++i) rb[i] = p[(size_t)i * ldb];
    }
  };
  auto storeB = [&](int buf, auto& rb) {  // pack 8 k-elems of one col -> one b128
    ushort8_t h;
    if constexpr (BF16B) {
      h = rb;
    } else {
#pragma unroll
      for (int i = 0; i < 8; ++i) {
        h[i] = f2bf(rb[i]);
        if constexpr (SUMSQ) ss += rb[i] * rb[i];
      }
    }
    *(uint4*)&SH[16384 + buf * 2048 + lane * 32 + wv * 8] = __builtin_bit_cast(uint4, h);
  };
  auto gllA = [&](int buf, int t) {      // 16 KB panel tile -> LDS, linear, coalesced
    const char* gp = (const char*)(pbase + (size_t)t * 8192) + wv * 4096 + lane * 16;
    char* lp = (char*)&SH[buf * 8192] + wv * 4096;
#pragma unroll
    for (int r = 0; r < 4; ++r) gll16(gp + r * 1024, lp + r * 1024);
  };

  f32x4 acc[4][4];
#pragma unroll
  for (int i = 0; i < 4; ++i)
#pragma unroll
    for (int j = 0; j < 4; ++j) acc[i][j] = (f32x4){0.f, 0.f, 0.f, 0.f};

  auto comp = [&](int buf) {
    const u16* as = &SH[buf * 8192];
    const u16* bs = &SH[16384 + buf * 2048];
    bf16x8 afr[4], bfr[4];
#pragma unroll
    for (int j = 0; j < 4; ++j)
      bfr[j] = *(const bf16x8*)(bs + (j * 16 + l15) * 32 + g * 8);
#pragma unroll
    for (int i = 0; i < 4; ++i)
      afr[i] = *(const bf16x8*)(as + (wv * 64 + i * 16 + l15) * 32 + g * 8);
#pragma unroll
    for (int i = 0; i < 4; ++i)
#pragma unroll
      for (int j = 0; j < 4; ++j)
        acc[i][j] = __builtin_amdgcn_mfma_f32_16x16x32_bf16(afr[i], bfr[j], acc[i][j], 0, 0, 0);
  };

  // prologue: A(0) in flight, B(0), B(1) in flight
  gllA(0, 0);
  loadB(rbE, 0);
  loadB(rbO, 1);
  const int last = steps - 1;

  for (int t = 0; t < steps; t += 2) {
    // even step t: compute buf0 (tile t)
    gllA(1, (t + 1 < last) ? t + 1 : last);
    storeB(0, rbE);                       // compiler auto-waits rbE's loads
    loadB(rbE, (t + 2 < last) ? t + 2 : last);
    asm volatile("s_waitcnt vmcnt(20) lgkmcnt(0)" ::: "memory");
    __builtin_amdgcn_s_barrier();
    __builtin_amdgcn_sched_barrier(0);
    comp(0);
    __builtin_amdgcn_sched_barrier(0);
    __builtin_amdgcn_s_barrier();
    // odd step t+1: compute buf1 (tile t+1)
    gllA(0, (t + 2 < last) ? t + 2 : last);
    storeB(1, rbO);
    loadB(rbO, (t + 3 < last) ? t + 3 : last);
    asm volatile("s_waitcnt vmcnt(20) lgkmcnt(0)" ::: "memory");
    __builtin_amdgcn_s_barrier();
    __builtin_amdgcn_sched_barrier(0);
    comp(1);
    __builtin_amdgcn_sched_barrier(0);
    __builtin_amdgcn_s_barrier();
  }
  // full drain before LDS reuse in epilogues
  asm volatile("s_waitcnt vmcnt(0) lgkmcnt(0)" ::: "memory");
  __builtin_amdgcn_s_barrier();

  // epilogues (C/D layout m89-verified: col = j*16+l15, row = wv*64+i*16+g*4+r)
  if constexpr (OUTKIND == 0) {          // f32 via LDS, two 128-row halves
    float* sf = (float*)SH;              // [128][68] f32
#pragma unroll
    for (int h = 0; h < 2; ++h) {
      __syncthreads();
      if ((wv >> 1) == h) {
#pragma unroll
        for (int i = 0; i < 4; ++i)
#pragma unroll
          for (int j = 0; j < 4; ++j)
#pragma unroll
            for (int r = 0; r < 4; ++r)
              sf[((wv & 1) * 64 + i * 16 + g * 4 + r) * 68 + j * 16 + l15] = acc[i][j][r];
      }
      __syncthreads();
#pragma unroll
      for (int e = 0; e < 8; ++e) {     // 2048 float4s = full 128x64 tile
        int idx2 = tid + e * 256;
        int m = idx2 >> 4, c4 = (idx2 & 15) * 4;
        float4 v = *(const float4*)(sf + m * 68 + c4);
        *(float4*)((float*)Cv + (size_t)(row0 + h * 128 + m) * ldc + col0 + c4) = v;
      }
    }
  } else if constexpr (OUTKIND == 1) {   // bf16 z-partial via LDS
    u16* C = (u16*)Cv + (size_t)bz * zstride;
    u16* sb = SH;                        // [256][72] u16
#pragma unroll
    for (int i = 0; i < 4; ++i)
#pragma unroll
      for (int j = 0; j < 4; ++j)
#pragma unroll
        for (int r = 0; r < 4; ++r)
          sb[(wv * 64 + i * 16 + g * 4 + r) * 72 + j * 16 + l15] = f2bf(acc[i][j][r]);
    __syncthreads();
#pragma unroll
    for (int e = 0; e < 8; ++e) {
      int m = (tid >> 3) + e * 32;
      uint4 v = *(const uint4*)(sb + m * 72 + (tid & 7) * 8);
      *(uint4*)(C + (size_t)m * ldc + col0 + (tid & 7) * 8) = v;
    }
  } else {                               // atomic f32
    float* C = (float*)Cv;
#pragma unroll
    for (int i = 0; i < 4; ++i)
#pragma unroll
      for (int j = 0; j < 4; ++j) {
        size_t base = (size_t)(row0 + wv * 64 + i * 16 + g * 4) * ldc + col0 + j * 16 + l15;
#pragma unroll
        for (int r = 0; r < 4; ++r) atomicAdd(C + base + (size_t)r * ldc, acc[i][j][r]);
      }
  }

  if constexpr (SUMSQ) {
#pragma unroll
    for (int o = 32; o; o >>= 1) ss += __shfl_xor(ss, o);
    if (lane == 0) sred[wv] = ss;
    __syncthreads();
    if (tid == 0) atomicAdd(sumsq, sred[0] + sred[1] + sred[2] + sred[3]);
  }
}

// ---------------- producers / small kernels ----------------
__launch_bounds__(256)
__global__ void cvtF_panel(const float* __restrict__ F, u16* __restrict__ pan) {
  int idx = blockIdx.x * 256 + threadIdx.x;      // 524288 groups of 8
  int m = idx >> 6, k0 = (idx & 63) * 8;
  float4 a = *(const float4*)(F + (size_t)m * Dd + k0);
  float4 b = *(const float4*)(F + (size_t)m * Dd + k0 + 4);
  ushort8_t h;
  h[0] = f2bf(a.x); h[1] = f2bf(a.y); h[2] = f2bf(a.z); h[3] = f2bf(a.w);
  h[4] = f2bf(b.x); h[5] = f2bf(b.y); h[6] = f2bf(b.z); h[7] = f2bf(b.w);
  int mb = m >> 8, mr = m & 255, p = k0 >> 5, c = k0 & 31;
  *(uint4*)(pan + ((size_t)(mb * 16 + p) * 256 + mr) * 32 + c) = __builtin_bit_cast(uint4, h);
}

__launch_bounds__(256)
__global__ void softmax_rows(float* __restrict__ io, const float* __restrict__ bias) {
  __shared__ float s1[4], s2[4];
  int n = blockIdx.x, k = threadIdx.x, w = k >> 6;
  size_t idx = (size_t)n * Kk + k;
  float x = io[idx] + bias[k];
  float m = x;
#pragma unroll
  for (int o = 32; o; o >>= 1) m = fmaxf(m, __shfl_xor(m, o));
  if ((k & 63) == 0) s1[w] = m;
  __syncthreads();
  m = fmaxf(fmaxf(s1[0], s1[1]), fmaxf(s1[2], s1[3]));
  float e = __expf(x - m);
  float sum = e;
#pragma unroll
  for (int o = 32; o; o >>= 1) sum += __shfl_xor(sum, o);
  if ((k & 63) == 0) s2[w] = sum;
  __syncthreads();
  sum = s2[0] + s2[1] + s2[2] + s2[3];
  io[idx] = e / sum;
}

__launch_bounds__(256)
__global__ void colsum_k(const float* __restrict__ a, float* __restrict__ cs) {
  int k = threadIdx.x;
  size_t n0 = (size_t)blockIdx.x * 32;
  float s = 0.f;
  for (int i = 0; i < 32; ++i) s += a[(n0 + i) * Kk + k];
  atomicAdd(&cs[k], s);
}

__launch_bounds__(256)
__global__ void make_sp(const float* __restrict__ a, const float* __restrict__ cs,
                        u16* __restrict__ sp, float* __restrict__ ent_sum) {
  __shared__ float s[4];
  int idx = blockIdx.x * 256 + threadIdx.x;
  float4 v = reinterpret_cast<const float4*>(a)[idx];
  int k0 = (idx << 2) & (Kk - 1);
  float p0 = v.x / (cs[k0 + 0] + 1e-8f);
  float p1 = v.y / (cs[k0 + 1] + 1e-8f);
  float p2 = v.z / (cs[k0 + 2] + 1e-8f);
  float p3 = v.w / (cs[k0 + 3] + 1e-8f);
  ushort4 o = {f2bf(p0), f2bf(p1), f2bf(p2), f2bf(p3)};
  reinterpret_cast<ushort4*>(sp)[idx] = o;
  float ent = -(p0 * __logf(p0 + 1e-15f) + p1 * __logf(p1 + 1e-15f) +
                p2 * __logf(p2 + 1e-15f) + p3 * __logf(p3 + 1e-15f));
#pragma unroll
  for (int oo = 32; oo; oo >>= 1) ent += __shfl_xor(ent, oo);
  if ((threadIdx.x & 63) == 0) s[threadIdx.x >> 6] = ent;
  __syncthreads();
  if (threadIdx.x == 0) atomicAdd(ent_sum, s[0] + s[1] + s[2] + s[3]);
}

// spT panel: block p handles n in [32p,32p+32), thread = k. Coalesced reads.
__launch_bounds__(256)
__global__ void make_spT_panel(const float* __restrict__ a, const float* __restrict__ cs,
                               u16* __restrict__ pan) {
  int p = blockIdx.x, k = threadIdx.x;
  float inv = 1.f / (cs[k] + 1e-8f);
  int n0 = p * 32;
  ushort8_t h0, h1, h2, h3;
#pragma unroll
  for (int j = 0; j < 8; ++j) h0[j] = f2bf(a[(size_t)(n0 + j) * Kk + k] * inv);
#pragma unroll
  for (int j = 0; j < 8; ++j) h1[j] = f2bf(a[(size_t)(n0 + 8 + j) * Kk + k] * inv);
#pragma unroll
  for (int j = 0; j < 8; ++j) h2[j] = f2bf(a[(size_t)(n0 + 16 + j) * Kk + k] * inv);
#pragma unroll
  for (int j = 0; j < 8; ++j) h3[j] = f2bf(a[(size_t)(n0 + 24 + j) * Kk + k] * inv);
  u16* dst = pan + ((size_t)p * 256 + k) * 32;
  *(uint4*)(dst + 0)  = __builtin_bit_cast(uint4, h0);
  *(uint4*)(dst + 8)  = __builtin_bit_cast(uint4, h1);
  *(uint4*)(dst + 16) = __builtin_bit_cast(uint4, h2);
  *(uint4*)(dst + 24) = __builtin_bit_cast(uint4, h3);
}

// sum 8 bf16 partials -> P panel
__launch_bounds__(256)
__global__ void combine_P(const u16* __restrict__ part, u16* __restrict__ pan) {
  int idx = blockIdx.x * 256 + threadIdx.x;      // 262144
  int m = idx >> 10, kk8 = idx & 1023;
  size_t off = (size_t)m * Nn + kk8 * 8;
  float8_t s = {0.f, 0.f, 0.f, 0.f, 0.f, 0.f, 0.f, 0.f};
#pragma unroll
  for (int z = 0; z < 8; ++z) {
    ushort8_t v = __builtin_bit_cast(ushort8_t,
        *(const uint4*)(part + (size_t)z * Kk * Nn + off));
#pragma unroll
    for (int j = 0; j < 8; ++j) s[j] += bf2f(v[j]);
  }
  ushort8_t h;
#pragma unroll
  for (int j = 0; j < 8; ++j) h[j] = f2bf(s[j]);
  int p = kk8 >> 2, c = (kk8 & 3) * 8;
  *(uint4*)(pan + ((size_t)p * 256 + m) * 32 + c) = __builtin_bit_cast(uint4, h);
}

__launch_bounds__(256)
__global__ void finalize_k(const float* __restrict__ ap, const float* __restrict__ spTsp,
                           const float* __restrict__ scal,
                           float* __restrict__ olink, float* __restrict__ oent) {
  __shared__ float s1[4], s2[4];
  int t = threadIdx.x;
  float tr = ap[t * (Kk + 1)];
#pragma unroll
  for (int o = 32; o; o >>= 1) tr += __shfl_xor(tr, o);
  if ((t & 63) == 0) s1[t >> 6] = tr;
  __syncthreads();
  float trace = s1[0] + s1[1] + s1[2] + s1[3];
  float fr = 0.f;
  for (int i = t; i < Kk * Kk; i += 256) { float v = spTsp[i]; fr += v * v; }
#pragma unroll
  for (int o = 32; o; o >>= 1) fr += __shfl_xor(fr, o);
  if ((t & 63) == 0) s2[t >> 6] = fr;
  __syncthreads();
  float fro = s2[0] + s2[1] + s2[2] + s2[3];
  if (t == 0) {
    float val = scal[0] - 2.f * trace + fro;
    *olink = sqrtf(fmaxf(val, 0.f)) / ((float)Nn * (float)Nn);
    *oent  = scal[1] / (float)Nn;
  }
}

// ---------------- launch ----------------
extern "C" void kernel_launch(void* const* d_in, const int* in_sizes, int n_in,
                              void* d_out, int out_size, void* d_ws, size_t ws_size,
                              hipStream_t stream) {
  const float* F    = (const float*)d_in[0];
  const float* Adj  = (const float*)d_in[1];
  const float* W    = (const float*)d_in[2];
  const float* bias = (const float*)d_in[3];
  float* out = (float*)d_out;
  char* ws = (char*)d_ws;

  u16*  FbfPan = (u16*)(ws + 0);           // 8 MB (dead after G1; overlaid by parts)
  u16*  parts  = (u16*)(ws + 0);           // 8 x 4 MB bf16 partials (32 MB)
  u16*  spb    = (u16*)(ws + 33554432);    // 4 MB
  u16*  spTpan = (u16*)(ws + 37748736);    // 4 MB
  u16*  Ppan   = (u16*)(ws + 41943040);    // 4 MB
  float* cs    = (float*)(ws + 46137344);  // 1 KB
  float* spTsp = (float*)(ws + 46138368);  // 256 KB
  float* scal  = (float*)(ws + 46400512);  // [0]=sumA2 [1]=ent

  float* fpool  = out;
  float* assign = out + 131072;
  float* apool  = out + 2228224;
  float* olink  = out + 2293760;
  float* oent   = out + 2293761;

  (void)hipMemsetAsync(fpool, 0, 131072 * 4, stream);
  (void)hipMemsetAsync(apool, 0, 65536 * 4, stream);
  (void)hipMemsetAsync(spTsp, 0, 65536 * 4, stream);
  (void)hipMemsetAsync(cs,    0, 256 * 4,   stream);
  (void)hipMemsetAsync(scal,  0, 8,         stream);

  cvtF_panel<<<2048, 256, 0, stream>>>(F, FbfPan);

  // G1: logits = F @ W (W f32 converted on the fly) -> assign, softmax in place
  gemm2<false, false, 0><<<dim3(4, 32, 1), 256, 0, stream>>>(
      FbfPan, 16, W, Kk, assign, Kk, Dd, 0, nullptr, 0);
  softmax_rows<<<Nn, 256, 0, stream>>>(assign, bias);
  colsum_k<<<256, 256, 0, stream>>>(assign, cs);
  make_sp<<<2048, 256, 0, stream>>>(assign, cs, spb, &scal[1]);
  make_spT_panel<<<256, 256, 0, stream>>>(assign, cs, spTpan);

  // G4: features_pooled = spT @ F (atomic over 16 k-chunks; B = F f32)
  gemm2<false, false, 2><<<dim3(8, 1, 16), 256, 0, stream>>>(
      spTpan, 256, F, Dd, fpool, Dd, Nn / 16, 0, nullptr, 0);
  // G5: spTsp = spT @ sp
  gemm2<true, false, 2><<<dim3(4, 1, 16), 256, 0, stream>>>(
      spTpan, 256, spb, Kk, spTsp, Kk, Nn / 16, 0, nullptr, 0);
  // G2: P = spT @ A: 8 bf16 partials + fused sum(A^2), XCD-chunked swizzle
  gemm2<false, true, 1><<<dim3(128, 1, 8), 256, 0, stream>>>(
      spTpan, 256, Adj, Nn, parts, Nn, Nn / 8, (size_t)Kk * Nn, &scal[0], 1);
  combine_P<<<1024, 256, 0, stream>>>(parts, Ppan);
  // G3: adjacency_pooled = P @ sp
  gemm2<true, false, 2><<<dim3(4, 1, 16), 256, 0, stream>>>(
      Ppan, 256, spb, Kk, apool, Kk, Nn / 16, 0, nullptr, 0);

  finalize_k<<<1, 256, 0, stream>>>(apool, spTsp, scal, olink, oent);
}